// Round 8
// baseline (191.085 us; speedup 1.0000x reference)
//
#include <hip/hip_runtime.h>

#define N_NODES 50000
#define N_EDGES 800000
#define D_FEAT 128
#define LN_EPS 1e-5f
#define TM 128         // nodes per block in gsage_main (4 row-slab waves)
#define CVT_B 3125     // blocks for cvt range (800000 threads)
#define NBUCK 391      // ceil(N_NODES/128) dst buckets for binned fill
#define BCAP 3072      // fixed bucket capacity (mean 2048, sigma 45 -> +22s)
#define BIN1_E 4096    // edges per binning block
#define BIN1_B 196     // ceil(N_EDGES/BIN1_E)

typedef __attribute__((ext_vector_type(8))) short bf16x8;
typedef __attribute__((ext_vector_type(4))) float f32x4;

__device__ __forceinline__ unsigned short f2bf(float f) {
    union { float f; unsigned int i; } v; v.f = f;
    unsigned int x = v.i;
    unsigned int lsb = (x >> 16) & 1u;
    x += 0x7fffu + lsb;          // RNE
    return (unsigned short)(x >> 16);
}
__device__ __forceinline__ float bflo(unsigned int u) {
    union { unsigned int i; float f; } v; v.i = u << 16; return v.f;
}
__device__ __forceinline__ float bfhi(unsigned int u) {
    union { unsigned int i; float f; } v; v.i = u & 0xffff0000u; return v.f;
}
__device__ __forceinline__ int clampn(int v) {
    return (v < 0) ? 0 : ((v >= N_NODES) ? (N_NODES - 1) : v);
}
// pack 2 floats -> (hi-bf16 pair, lo-bf16 pair)
__device__ __forceinline__ void split2(float f0, float f1,
                                       unsigned int& hp, unsigned int& lp) {
    unsigned short h0 = f2bf(f0), h1 = f2bf(f1);
    unsigned short l0 = f2bf(f0 - bflo(h0)), l1 = f2bf(f1 - bflo(h1));
    hp = ((unsigned)h1 << 16) | h0;
    lp = ((unsigned)l1 << 16) | l0;
}

// ---------------------------------------------------------------------------
// prep kernel: block-range-split union of
//   [0, CVT_B)            : x fp32 -> AH/AL x-half (bf16 hi/lo planes)
//   [CVT_B, +BIN1_B)      : binpass1 (independent of cvt outputs; overlaps
//                           atomic-bound binning under BW-bound cvt)
//   [CVT_B+BIN1_B, +128)  : wprep row t (fused weight, bf16 hi/lo split,
//                           stored TRANSPOSED [col][k] for MFMA B-frags)
// ---------------------------------------------------------------------------
__global__ __launch_bounds__(256) void prep_kernel(
        const float* __restrict__ x,
        const int* __restrict__ ei,
        const float* __restrict__ agg_W,
        const float* __restrict__ agg_b,
        const float* __restrict__ W,
        const float* __restrict__ b,
        uint4* __restrict__ AH4,
        uint4* __restrict__ AL4,
        unsigned int* __restrict__ bcurs,
        unsigned int* __restrict__ binned,
        unsigned short* __restrict__ Wt2h,
        unsigned short* __restrict__ Wt2l,
        float* __restrict__ cvec)
{
    __shared__ int esrc[BIN1_E];               // 16 KB
    __shared__ unsigned short edst[BIN1_E];    // 8 KB
    __shared__ int hist[NBUCK];
    __shared__ unsigned int cur2[NBUCK];

    int blk = blockIdx.x;
    if (blk < CVT_B) {
        int i = blk * 256 + threadIdx.x;      // 800000 threads, 8 floats each
        const float4 a = *(const float4*)(x + (size_t)i * 8);
        const float4 c = *(const float4*)(x + (size_t)i * 8 + 4);
        uint4 h, l;
        split2(a.x, a.y, h.x, l.x);
        split2(a.z, a.w, h.y, l.y);
        split2(c.x, c.y, h.z, l.z);
        split2(c.z, c.w, h.w, l.w);
        size_t idx = (size_t)(i >> 4) * 32 + (i & 15);   // row*32 + col-chunk
        AH4[idx] = h;
        AL4[idx] = l;
    } else if (blk < CVT_B + BIN1_B) {
        // ---- binpass1 leg: LDS-staged edges, fixed-capacity buckets ----
        int t    = threadIdx.x;
        int base = (blk - CVT_B) * BIN1_E;

        for (int i = t; i < NBUCK; i += 256) hist[i] = 0;
        #pragma unroll
        for (int i = 0; i < BIN1_E / 256; ++i) {
            int idx = i * 256 + t;
            int e = base + idx;
            if (e < N_EDGES) {
                esrc[idx] = clampn(ei[e]);
                edst[idx] = (unsigned short)clampn(ei[N_EDGES + e]);
            } else {
                esrc[idx] = -1;
            }
        }
        __syncthreads();

        #pragma unroll
        for (int i = 0; i < BIN1_E / 256; ++i) {
            int idx = i * 256 + t;
            if (esrc[idx] >= 0) atomicAdd(&hist[(int)edst[idx] >> 7], 1);
        }
        __syncthreads();

        for (int bk = t; bk < NBUCK; bk += 256) {
            int c = hist[bk];
            unsigned int off = c ? atomicAdd(&bcurs[bk], (unsigned int)c) : 0u;
            cur2[bk] = (unsigned int)bk * BCAP + off;
        }
        __syncthreads();

        #pragma unroll
        for (int i = 0; i < BIN1_E / 256; ++i) {
            int idx = i * 256 + t;
            int src = esrc[idx];
            if (src >= 0) {
                int dst = (int)edst[idx];
                int bk  = dst >> 7;
                unsigned int slot = atomicAdd(&cur2[bk], 1u);
                if (slot < (unsigned int)bk * BCAP + BCAP)     // capacity guard
                    binned[slot] = (unsigned int)src | ((unsigned int)dst << 16);
            }
        }
    } else {
        int t = blk - CVT_B - BIN1_B;         // 0..127 (k row)
        int n = threadIdx.x;
        if (n < 128) {
            float w1 = W[t * 128 + n];                      // k=t, col=n
            unsigned short h1 = f2bf(w1);
            Wt2h[n * 256 + t] = h1;
            Wt2l[n * 256 + t] = f2bf(w1 - bflo(h1));
            float m = 0.0f;
            for (int j = 0; j < 128; ++j)
                m += agg_W[t * 128 + j] * W[(128 + j) * 128 + n];
            unsigned short h2 = f2bf(m);                    // k=128+t, col=n
            Wt2h[n * 256 + 128 + t] = h2;
            Wt2l[n * 256 + 128 + t] = f2bf(m - bflo(h2));
            if (t == 0) {
                float s = b[n];
                for (int j = 0; j < 128; ++j)
                    s += agg_b[j] * W[(128 + j) * 128 + n];
                cvec[n] = s;
            }
        }
    }
}

// ---------------------------------------------------------------------------
// binpass2: one block per bucket at fixed base bk*BCAP.  Derives per-node
// degree (LDS count) and bucket-local CSR positions (128-wide LDS scan),
// writes deg_cnt / pos (=end), then scatters src (u16) into the bucket's
// contiguous edge_src region (L2-hot).
// ---------------------------------------------------------------------------
__global__ __launch_bounds__(512) void binpass2_kernel(const unsigned int* __restrict__ binned,
                                                       const unsigned int* __restrict__ bcurs,
                                                       int* __restrict__ pos,
                                                       int* __restrict__ deg_cnt,
                                                       unsigned short* __restrict__ edge_src)
{
    __shared__ int lscan[128];
    __shared__ int lcnt[128];
    __shared__ int lcur[128];
    int bk = blockIdx.x, t = threadIdx.x;

    unsigned int cnt = bcurs[bk]; if (cnt > BCAP) cnt = BCAP;
    unsigned int start = (unsigned int)bk * BCAP;
    unsigned int end   = start + cnt;

    int n0 = bk << 7;
    int nn = N_NODES - n0; if (nn > 128) nn = 128;

    if (t < 128) lcnt[t] = 0;
    __syncthreads();
    for (unsigned int e = start + t; e < end; e += 512)
        atomicAdd(&lcnt[(int)(binned[e] >> 16) & 127], 1);
    __syncthreads();

    // exclusive scan of lcnt[128]
    int lv = (t < 128) ? lcnt[t] : 0;
    if (t < 128) lscan[t] = lv;
    __syncthreads();
    for (int off = 1; off < 128; off <<= 1) {
        int u = (t >= off && t < 128) ? lscan[t - off] : 0;
        __syncthreads();
        if (t < 128) lscan[t] += u;
        __syncthreads();
    }
    if (t < 128) {
        int ls = (int)start + lscan[t] - lv;  // node start (bucket-local CSR)
        lcur[t] = ls;
        if (t < nn) {
            pos[n0 + t]     = ls + lv;        // = end (gather's convention)
            deg_cnt[n0 + t] = lv;
        }
    }
    __syncthreads();

    for (unsigned int e = start + t; e < end; e += 512) {
        unsigned int v = binned[e];
        int slot = atomicAdd(&lcur[(int)(v >> 16) & 127], 1);
        edge_src[slot] = (unsigned short)(v & 0xffffu);
    }
}

// ---------------------------------------------------------------------------
// gather: one wave per node, 4 edges per iteration (quarter-wave per edge,
// uint4 = 8 bf16 hi feats per lane).  Reads AH x-half rows (random, L2/LLC-
// hot); writes the mean into AH/AL agg-half (bf16 hi/lo split -> identical
// numerics to the in-register GEMM split).
// ---------------------------------------------------------------------------
__global__ void gather_kernel(uint4* __restrict__ AH4,
                              uint4* __restrict__ AL4,
                              const int* __restrict__ pos,    // = end
                              const int* __restrict__ deg_cnt,
                              const unsigned short* __restrict__ edge_src)
{
    int tid  = threadIdx.x;
    int node = blockIdx.x * 4 + (tid >> 6);
    int lane = tid & 63;
    int quarter = lane >> 4;
    int sub     = lane & 15;
    if (node >= N_NODES) return;

    int end   = pos[node];
    int dcnt  = deg_cnt[node];
    int start = end - dcnt;

    float a0 = 0.f, a1 = 0.f, a2 = 0.f, a3 = 0.f,
          a4 = 0.f, a5 = 0.f, a6 = 0.f, a7 = 0.f;

    for (int b = start; b < end; b += 64) {
        int nb = end - b; if (nb > 64) nb = 64;
        int sid = (b + lane < end) ? (int)edge_src[b + lane] : 0;
        for (int j = 0; j < nb; j += 4) {
            int eidx = j + quarter;
            int s = __shfl(sid, eidx, 64);
            if (eidx < nb) {
                const uint4 v = AH4[(size_t)s * 32 + sub];   // x-half of row s
                a0 += bflo(v.x); a1 += bfhi(v.x);
                a2 += bflo(v.y); a3 += bfhi(v.y);
                a4 += bflo(v.z); a5 += bfhi(v.z);
                a6 += bflo(v.w); a7 += bfhi(v.w);
            }
        }
    }
    #pragma unroll
    for (int m = 16; m <= 32; m <<= 1) {
        a0 += __shfl_xor(a0, m, 64); a1 += __shfl_xor(a1, m, 64);
        a2 += __shfl_xor(a2, m, 64); a3 += __shfl_xor(a3, m, 64);
        a4 += __shfl_xor(a4, m, 64); a5 += __shfl_xor(a5, m, 64);
        a6 += __shfl_xor(a6, m, 64); a7 += __shfl_xor(a7, m, 64);
    }
    if (quarter == 0) {
        float inv = 1.0f / (float)((dcnt > 1) ? dcnt : 1);
        uint4 h, l;
        split2(a0 * inv, a1 * inv, h.x, l.x);
        split2(a2 * inv, a3 * inv, h.y, l.y);
        split2(a4 * inv, a5 * inv, h.z, l.z);
        split2(a6 * inv, a7 * inv, h.w, l.w);
        size_t idx = (size_t)node * 32 + 16 + sub;           // agg-half
        AH4[idx] = h;
        AL4[idx] = l;
    }
}

// ---------------------------------------------------------------------------
// MFMA GEMM v3 (barrier-free, LDS-free): A = AH/AL planes ([row][256] bf16
// hi/lo) x Wt2 (bf16 hi/lo, [col][k]) -> Ahi*Whi + Alo*Whi + Ahi*Wlo.
// Wt2 (128 KB) is L2/LLC-resident (read by all 391 blocks), so B-fragments
// load DIRECTLY from global -- no LDS staging, no __syncthreads at all; each
// wave is fully independent.  B-frag coalescing = 16 cols x 64 contiguous
// bytes per wave instruction (same pattern as A).  Identical bits in
// identical MFMA order as the staged version -> bit-identical output.
// Block = 128 nodes, 4 row-slab waves (32 rows x 128 cols, M_rep=2, N_rep=8).
// Out-of-range rows clamp (loads valid junk; outputs guarded).
// ---------------------------------------------------------------------------
__global__ __launch_bounds__(256) void gsage_main(
        const unsigned short* __restrict__ AH,
        const unsigned short* __restrict__ AL,
        const unsigned short* __restrict__ Wt2h,
        const unsigned short* __restrict__ Wt2l,
        const float* __restrict__ cvec,
        const float* __restrict__ gamma,
        const float* __restrict__ beta,
        float* __restrict__ out)
{
    int tid  = threadIdx.x;
    int lane = tid & 63;
    int w    = tid >> 6;                 // row-slab 0..3 (32 rows each)
    int l15  = lane & 15, grp = lane >> 4;
    int node0 = blockIdx.x * TM;

    f32x4 acc[2][8];
    #pragma unroll
    for (int m = 0; m < 2; ++m)
        #pragma unroll
        for (int nf = 0; nf < 8; ++nf)
            acc[m][nf] = (f32x4){0.f, 0.f, 0.f, 0.f};

    int row0 = node0 + w * 32 + l15;     // A-frag row for m=0
    int rA0 = (row0      < N_NODES) ? row0      : (N_NODES - 1);
    int rA1 = (row0 + 16 < N_NODES) ? row0 + 16 : (N_NODES - 1);
    const unsigned short* pAH0 = AH + (size_t)rA0 * 256;
    const unsigned short* pAL0 = AL + (size_t)rA0 * 256;
    const unsigned short* pAH1 = AH + (size_t)rA1 * 256;
    const unsigned short* pAL1 = AL + (size_t)rA1 * 256;
    const unsigned short* pB   = Wt2h + (size_t)l15 * 256;   // col base (nf adds 16*256)
    const unsigned short* pBl  = Wt2l + (size_t)l15 * 256;

    #pragma unroll
    for (int c = 0; c < 4; ++c) {
        #pragma unroll
        for (int ks = 0; ks < 2; ++ks) {
            int krel = c * 64 + ks * 32 + grp * 8;       // 0..248 over [x|agg] row

            bf16x8 ah0 = *(const bf16x8*)(pAH0 + krel);
            bf16x8 al0 = *(const bf16x8*)(pAL0 + krel);
            bf16x8 ah1 = *(const bf16x8*)(pAH1 + krel);
            bf16x8 al1 = *(const bf16x8*)(pAL1 + krel);

            #pragma unroll
            for (int nf = 0; nf < 8; ++nf) {
                bf16x8 bh = *(const bf16x8*)(pB  + (size_t)nf * 16 * 256 + krel);
                bf16x8 bl = *(const bf16x8*)(pBl + (size_t)nf * 16 * 256 + krel);
                acc[0][nf] = __builtin_amdgcn_mfma_f32_16x16x32_bf16(ah0, bh, acc[0][nf], 0, 0, 0);
                acc[0][nf] = __builtin_amdgcn_mfma_f32_16x16x32_bf16(al0, bh, acc[0][nf], 0, 0, 0);
                acc[0][nf] = __builtin_amdgcn_mfma_f32_16x16x32_bf16(ah0, bl, acc[0][nf], 0, 0, 0);
                acc[1][nf] = __builtin_amdgcn_mfma_f32_16x16x32_bf16(ah1, bh, acc[1][nf], 0, 0, 0);
                acc[1][nf] = __builtin_amdgcn_mfma_f32_16x16x32_bf16(al1, bh, acc[1][nf], 0, 0, 0);
                acc[1][nf] = __builtin_amdgcn_mfma_f32_16x16x32_bf16(ah1, bl, acc[1][nf], 0, 0, 0);
            }
        }
    }

    // ---- epilogue: +c, ReLU, LayerNorm over 128 cols (wave-local) ----
    float cv[8], gv[8], bv[8];
    #pragma unroll
    for (int nf = 0; nf < 8; ++nf) {
        int col = nf * 16 + l15;
        cv[nf] = cvec[col]; gv[nf] = gamma[col]; bv[nf] = beta[col];
    }

    #pragma unroll
    for (int m = 0; m < 2; ++m) {
        #pragma unroll
        for (int r = 0; r < 4; ++r) {
            float s1 = 0.f, s2 = 0.f;
            #pragma unroll
            for (int nf = 0; nf < 8; ++nf) {
                float v = acc[m][nf][r] + cv[nf];
                v = (v > 0.f) ? v : 0.f;
                acc[m][nf][r] = v;
                s1 += v; s2 += v * v;
            }
            #pragma unroll
            for (int msk = 1; msk < 16; msk <<= 1) {
                s1 += __shfl_xor(s1, msk, 64);
                s2 += __shfl_xor(s2, msk, 64);
            }
            float mu   = s1 * (1.0f / 128.0f);
            float var  = s2 * (1.0f / 128.0f) - mu * mu;
            float rstd = rsqrtf(var + LN_EPS);
            int node = node0 + w * 32 + m * 16 + grp * 4 + r;
            if (node < N_NODES) {
                #pragma unroll
                for (int nf = 0; nf < 8; ++nf)
                    out[(size_t)node * D_FEAT + nf * 16 + l15] =
                        (acc[m][nf][r] - mu) * rstd * gv[nf] + bv[nf];
            }
        }
    }
}

// ---------------------------------------------------------------------------
extern "C" void kernel_launch(void* const* d_in, const int* in_sizes, int n_in,
                              void* d_out, int out_size, void* d_ws, size_t ws_size,
                              hipStream_t stream) {
    const float* x     = (const float*)d_in[0];
    const int*   ei    = (const int*)d_in[1];
    const float* agg_W = (const float*)d_in[2];
    const float* agg_b = (const float*)d_in[3];
    const float* W     = (const float*)d_in[4];
    const float* b     = (const float*)d_in[5];
    const float* gamma = (const float*)d_in[6];
    const float* beta  = (const float*)d_in[7];
    float*       out   = (float*)d_out;

    size_t out_bytes = (size_t)out_size * sizeof(float);

    if (n_in != 8)                       { hipMemsetAsync(d_out, 0x45, out_bytes, stream); return; }
    if (in_sizes[0] != N_NODES * D_FEAT) { hipMemsetAsync(d_out, 0x48, out_bytes, stream); return; }
    if (in_sizes[1] != 2 * N_EDGES)      { hipMemsetAsync(d_out, 0x49, out_bytes, stream); return; }
    if (out_size != N_NODES * D_FEAT)    { hipMemsetAsync(d_out, 0x47, out_bytes, stream); return; }

    // workspace layout (4-byte elements)
    int*   deg_cnt  = (int*)d_ws;                  // 50000
    int*   pos      = deg_cnt + N_NODES;           // 50000
    unsigned short* edge_src = (unsigned short*)(pos + N_NODES);   // NBUCK*BCAP u16
    unsigned short* Wt2h = (unsigned short*)((int*)edge_src + N_EDGES);  // 128*256 bf16
    unsigned short* Wt2l = Wt2h + 128 * 256;                       // 128*256 bf16
    float* cvec     = (float*)(Wt2l + 128 * 256);  // 128
    unsigned short* AH = (unsigned short*)(cvec + 128);            // 50000*256 bf16
    unsigned short* AL = AH + (size_t)N_NODES * 256;               // 50000*256 bf16
    size_t need_ws = ((size_t)N_NODES * 2 + N_EDGES + 256 * 128 + 128) * 4
                     + (size_t)N_NODES * 256 * 2 * 2;
    if (ws_size < need_ws)               { hipMemsetAsync(d_out, 0x46, out_bytes, stream); return; }

    // binned edges + bucket cursors live in d_out (dead until gsage writes out)
    unsigned int* binned = (unsigned int*)d_out;   // NBUCK*BCAP u32 = 4.8 MB
    unsigned int* bcurs  = binned + (size_t)NBUCK * BCAP;     // NBUCK

    hipMemsetAsync(bcurs, 0, NBUCK * sizeof(unsigned int), stream);
    prep_kernel<<<CVT_B + BIN1_B + 128, 256, 0, stream>>>(
        x, ei, agg_W, agg_b, W, b, (uint4*)AH, (uint4*)AL, bcurs, binned,
        Wt2h, Wt2l, cvec);
    binpass2_kernel<<<NBUCK, 512, 0, stream>>>(binned, bcurs, pos, deg_cnt, edge_src);
    gather_kernel<<<(N_NODES + 3) / 4, 256, 0, stream>>>(
        (uint4*)AH, (uint4*)AL, pos, deg_cnt, edge_src);
    gsage_main<<<(N_NODES + TM - 1) / TM, 256, 0, stream>>>(
        AH, AL, Wt2h, Wt2l, cvec, gamma, beta, out);
}

// Round 9
// 189.895 us; speedup vs baseline: 1.0063x; 1.0063x over previous
//
#include <hip/hip_runtime.h>

#define N_NODES 50000
#define N_EDGES 800000
#define D_FEAT 128
#define LN_EPS 1e-5f
#define TM 128         // nodes per block in gsage_main (4 row-slab waves)
#define CVT_B 3125     // blocks for cvt range (800000 threads)
#define NBUCK 391      // ceil(N_NODES/128) dst buckets for binned fill
#define BCAP 3072      // fixed bucket capacity (mean 2048, sigma 45 -> +22s)
#define BIN1_E 4096    // edges per binning block
#define BIN1_B 196     // ceil(N_EDGES/BIN1_E)

typedef __attribute__((ext_vector_type(8))) short bf16x8;
typedef __attribute__((ext_vector_type(4))) float f32x4;

__device__ __forceinline__ unsigned short f2bf(float f) {
    union { float f; unsigned int i; } v; v.f = f;
    unsigned int x = v.i;
    unsigned int lsb = (x >> 16) & 1u;
    x += 0x7fffu + lsb;          // RNE
    return (unsigned short)(x >> 16);
}
__device__ __forceinline__ float bflo(unsigned int u) {
    union { unsigned int i; float f; } v; v.i = u << 16; return v.f;
}
__device__ __forceinline__ float bfhi(unsigned int u) {
    union { unsigned int i; float f; } v; v.i = u & 0xffff0000u; return v.f;
}
__device__ __forceinline__ int clampn(int v) {
    return (v < 0) ? 0 : ((v >= N_NODES) ? (N_NODES - 1) : v);
}
// pack 2 floats -> (hi-bf16 pair, lo-bf16 pair)
__device__ __forceinline__ void split2(float f0, float f1,
                                       unsigned int& hp, unsigned int& lp) {
    unsigned short h0 = f2bf(f0), h1 = f2bf(f1);
    unsigned short l0 = f2bf(f0 - bflo(h0)), l1 = f2bf(f1 - bflo(h1));
    hp = ((unsigned)h1 << 16) | h0;
    lp = ((unsigned)l1 << 16) | l0;
}

// ---------------------------------------------------------------------------
// prep kernel: block-range-split union of
//   [0, CVT_B)            : x fp32 -> AH/AL x-half (bf16 hi/lo planes)
//   [CVT_B, +BIN1_B)      : binpass1 (independent of cvt outputs; overlaps
//                           atomic-bound binning under BW-bound cvt)
//   [CVT_B+BIN1_B, +128)  : wprep row t (fused weight, bf16 hi/lo split,
//                           stored TRANSPOSED [col][k] for MFMA B-frags)
// ---------------------------------------------------------------------------
__global__ __launch_bounds__(256) void prep_kernel(
        const float* __restrict__ x,
        const int* __restrict__ ei,
        const float* __restrict__ agg_W,
        const float* __restrict__ agg_b,
        const float* __restrict__ W,
        const float* __restrict__ b,
        uint4* __restrict__ AH4,
        uint4* __restrict__ AL4,
        unsigned int* __restrict__ bcurs,
        unsigned int* __restrict__ binned,
        unsigned short* __restrict__ Wt2h,
        unsigned short* __restrict__ Wt2l,
        float* __restrict__ cvec)
{
    __shared__ int esrc[BIN1_E];               // 16 KB
    __shared__ unsigned short edst[BIN1_E];    // 8 KB
    __shared__ int hist[NBUCK];
    __shared__ unsigned int cur2[NBUCK];

    int blk = blockIdx.x;
    if (blk < CVT_B) {
        int i = blk * 256 + threadIdx.x;      // 800000 threads, 8 floats each
        const float4 a = *(const float4*)(x + (size_t)i * 8);
        const float4 c = *(const float4*)(x + (size_t)i * 8 + 4);
        uint4 h, l;
        split2(a.x, a.y, h.x, l.x);
        split2(a.z, a.w, h.y, l.y);
        split2(c.x, c.y, h.z, l.z);
        split2(c.z, c.w, h.w, l.w);
        size_t idx = (size_t)(i >> 4) * 32 + (i & 15);   // row*32 + col-chunk
        AH4[idx] = h;
        AL4[idx] = l;
    } else if (blk < CVT_B + BIN1_B) {
        // ---- binpass1 leg: LDS-staged edges, fixed-capacity buckets ----
        int t    = threadIdx.x;
        int base = (blk - CVT_B) * BIN1_E;

        for (int i = t; i < NBUCK; i += 256) hist[i] = 0;
        #pragma unroll
        for (int i = 0; i < BIN1_E / 256; ++i) {
            int idx = i * 256 + t;
            int e = base + idx;
            if (e < N_EDGES) {
                esrc[idx] = clampn(ei[e]);
                edst[idx] = (unsigned short)clampn(ei[N_EDGES + e]);
            } else {
                esrc[idx] = -1;
            }
        }
        __syncthreads();

        #pragma unroll
        for (int i = 0; i < BIN1_E / 256; ++i) {
            int idx = i * 256 + t;
            if (esrc[idx] >= 0) atomicAdd(&hist[(int)edst[idx] >> 7], 1);
        }
        __syncthreads();

        for (int bk = t; bk < NBUCK; bk += 256) {
            int c = hist[bk];
            unsigned int off = c ? atomicAdd(&bcurs[bk], (unsigned int)c) : 0u;
            cur2[bk] = (unsigned int)bk * BCAP + off;
        }
        __syncthreads();

        #pragma unroll
        for (int i = 0; i < BIN1_E / 256; ++i) {
            int idx = i * 256 + t;
            int src = esrc[idx];
            if (src >= 0) {
                int dst = (int)edst[idx];
                int bk  = dst >> 7;
                unsigned int slot = atomicAdd(&cur2[bk], 1u);
                if (slot < (unsigned int)bk * BCAP + BCAP)     // capacity guard
                    binned[slot] = (unsigned int)src | ((unsigned int)dst << 16);
            }
        }
    } else {
        int t = blk - CVT_B - BIN1_B;         // 0..127 (k row)
        int n = threadIdx.x;
        if (n < 128) {
            float w1 = W[t * 128 + n];                      // k=t, col=n
            unsigned short h1 = f2bf(w1);
            Wt2h[n * 256 + t] = h1;
            Wt2l[n * 256 + t] = f2bf(w1 - bflo(h1));
            float m = 0.0f;
            for (int j = 0; j < 128; ++j)
                m += agg_W[t * 128 + j] * W[(128 + j) * 128 + n];
            unsigned short h2 = f2bf(m);                    // k=128+t, col=n
            Wt2h[n * 256 + 128 + t] = h2;
            Wt2l[n * 256 + 128 + t] = f2bf(m - bflo(h2));
            if (t == 0) {
                float s = b[n];
                for (int j = 0; j < 128; ++j)
                    s += agg_b[j] * W[(128 + j) * 128 + n];
                cvec[n] = s;
            }
        }
    }
}

// ---------------------------------------------------------------------------
// binpass2: one block per bucket at fixed base bk*BCAP.  Derives per-node
// degree (LDS count) and bucket-local CSR positions (128-wide LDS scan),
// writes deg_cnt / pos (=end), then scatters src (u16) into the bucket's
// contiguous edge_src region (L2-hot).
// ---------------------------------------------------------------------------
__global__ __launch_bounds__(512) void binpass2_kernel(const unsigned int* __restrict__ binned,
                                                       const unsigned int* __restrict__ bcurs,
                                                       int* __restrict__ pos,
                                                       int* __restrict__ deg_cnt,
                                                       unsigned short* __restrict__ edge_src)
{
    __shared__ int lscan[128];
    __shared__ int lcnt[128];
    __shared__ int lcur[128];
    int bk = blockIdx.x, t = threadIdx.x;

    unsigned int cnt = bcurs[bk]; if (cnt > BCAP) cnt = BCAP;
    unsigned int start = (unsigned int)bk * BCAP;
    unsigned int end   = start + cnt;

    int n0 = bk << 7;
    int nn = N_NODES - n0; if (nn > 128) nn = 128;

    if (t < 128) lcnt[t] = 0;
    __syncthreads();
    for (unsigned int e = start + t; e < end; e += 512)
        atomicAdd(&lcnt[(int)(binned[e] >> 16) & 127], 1);
    __syncthreads();

    // exclusive scan of lcnt[128]
    int lv = (t < 128) ? lcnt[t] : 0;
    if (t < 128) lscan[t] = lv;
    __syncthreads();
    for (int off = 1; off < 128; off <<= 1) {
        int u = (t >= off && t < 128) ? lscan[t - off] : 0;
        __syncthreads();
        if (t < 128) lscan[t] += u;
        __syncthreads();
    }
    if (t < 128) {
        int ls = (int)start + lscan[t] - lv;  // node start (bucket-local CSR)
        lcur[t] = ls;
        if (t < nn) {
            pos[n0 + t]     = ls + lv;        // = end (gather's convention)
            deg_cnt[n0 + t] = lv;
        }
    }
    __syncthreads();

    for (unsigned int e = start + t; e < end; e += 512) {
        unsigned int v = binned[e];
        int slot = atomicAdd(&lcur[(int)(v >> 16) & 127], 1);
        edge_src[slot] = (unsigned short)(v & 0xffffu);
    }
}

// ---------------------------------------------------------------------------
// gather: one wave per node, 4 edges per iteration (quarter-wave per edge,
// uint4 = 8 bf16 hi feats per lane).  Reads AH x-half rows (random, L2/LLC-
// hot); writes the mean into AH/AL agg-half (bf16 hi/lo split -> identical
// numerics to the in-register GEMM split).
// ---------------------------------------------------------------------------
__global__ void gather_kernel(uint4* __restrict__ AH4,
                              uint4* __restrict__ AL4,
                              const int* __restrict__ pos,    // = end
                              const int* __restrict__ deg_cnt,
                              const unsigned short* __restrict__ edge_src)
{
    int tid  = threadIdx.x;
    int node = blockIdx.x * 4 + (tid >> 6);
    int lane = tid & 63;
    int quarter = lane >> 4;
    int sub     = lane & 15;
    if (node >= N_NODES) return;

    int end   = pos[node];
    int dcnt  = deg_cnt[node];
    int start = end - dcnt;

    float a0 = 0.f, a1 = 0.f, a2 = 0.f, a3 = 0.f,
          a4 = 0.f, a5 = 0.f, a6 = 0.f, a7 = 0.f;

    for (int b = start; b < end; b += 64) {
        int nb = end - b; if (nb > 64) nb = 64;
        int sid = (b + lane < end) ? (int)edge_src[b + lane] : 0;
        for (int j = 0; j < nb; j += 4) {
            int eidx = j + quarter;
            int s = __shfl(sid, eidx, 64);
            if (eidx < nb) {
                const uint4 v = AH4[(size_t)s * 32 + sub];   // x-half of row s
                a0 += bflo(v.x); a1 += bfhi(v.x);
                a2 += bflo(v.y); a3 += bfhi(v.y);
                a4 += bflo(v.z); a5 += bfhi(v.z);
                a6 += bflo(v.w); a7 += bfhi(v.w);
            }
        }
    }
    #pragma unroll
    for (int m = 16; m <= 32; m <<= 1) {
        a0 += __shfl_xor(a0, m, 64); a1 += __shfl_xor(a1, m, 64);
        a2 += __shfl_xor(a2, m, 64); a3 += __shfl_xor(a3, m, 64);
        a4 += __shfl_xor(a4, m, 64); a5 += __shfl_xor(a5, m, 64);
        a6 += __shfl_xor(a6, m, 64); a7 += __shfl_xor(a7, m, 64);
    }
    if (quarter == 0) {
        float inv = 1.0f / (float)((dcnt > 1) ? dcnt : 1);
        uint4 h, l;
        split2(a0 * inv, a1 * inv, h.x, l.x);
        split2(a2 * inv, a3 * inv, h.y, l.y);
        split2(a4 * inv, a5 * inv, h.z, l.z);
        split2(a6 * inv, a7 * inv, h.w, l.w);
        size_t idx = (size_t)node * 32 + 16 + sub;           // agg-half
        AH4[idx] = h;
        AL4[idx] = l;
    }
}

// ---------------------------------------------------------------------------
// MFMA GEMM (R7 structure + T14 async-stage): A = AH/AL planes ([row][256]
// bf16 hi/lo) x Wt2 (bf16 hi/lo, [col][k]) -> Ahi*Whi + Alo*Whi + Ahi*Wlo.
// LDS-staged B (R8's direct-global B was L2-LATENCY-bound: 45us vs ~27us —
// bandwidth-residency does not excuse removing the latency-amortizing tier).
// T14: next chunk's 4x uint4 loaded into REGISTERS before computing the
// current chunk (HBM/L2 latency hides under ~400cy of MFMA), ds_write after
// the barrier.  Same bits, same MFMA order -> bit-identical output.
// Block = 128 nodes, 4 row-slab waves (32 rows x 128 cols, M_rep=2, N_rep=8);
// LayerNorm wave-local.
// ---------------------------------------------------------------------------
__global__ __launch_bounds__(256) void gsage_main(
        const unsigned short* __restrict__ AH,
        const unsigned short* __restrict__ AL,
        const unsigned short* __restrict__ Wt2h,
        const unsigned short* __restrict__ Wt2l,
        const float* __restrict__ cvec,
        const float* __restrict__ gamma,
        const float* __restrict__ beta,
        float* __restrict__ out)
{
    __shared__ unsigned short Bh[128][72];   // 18 KB (144B row stride, conflict-free b128)
    __shared__ unsigned short Bl[128][72];   // 18 KB

    int tid  = threadIdx.x;
    int lane = tid & 63;
    int w    = tid >> 6;                 // row-slab 0..3 (32 rows each)
    int l15  = lane & 15, grp = lane >> 4;
    int node0 = blockIdx.x * TM;

    // staging: thread -> (col, half-row) of the 128x64 bf16 chunk
    int scol  = tid >> 1;
    int spart = tid & 1;
    const uint4* srcH = (const uint4*)Wt2h + scol * 32 + spart * 4;
    const uint4* srcL = (const uint4*)Wt2l + scol * 32 + spart * 4;
    uint4* dstH = (uint4*)&Bh[scol][spart * 32];
    uint4* dstL = (uint4*)&Bl[scol][spart * 32];

    // prologue: stage chunk 0
    uint4 rH[4], rL[4];
    #pragma unroll
    for (int j = 0; j < 4; ++j) { rH[j] = srcH[j]; rL[j] = srcL[j]; }
    #pragma unroll
    for (int j = 0; j < 4; ++j) { dstH[j] = rH[j]; dstL[j] = rL[j]; }

    f32x4 acc[2][8];
    #pragma unroll
    for (int m = 0; m < 2; ++m)
        #pragma unroll
        for (int nf = 0; nf < 8; ++nf)
            acc[m][nf] = (f32x4){0.f, 0.f, 0.f, 0.f};

    int row0 = node0 + w * 32 + l15;     // A-frag row for m=0
    int rA0 = (row0      < N_NODES) ? row0      : (N_NODES - 1);
    int rA1 = (row0 + 16 < N_NODES) ? row0 + 16 : (N_NODES - 1);
    const unsigned short* pAH0 = AH + (size_t)rA0 * 256;
    const unsigned short* pAL0 = AL + (size_t)rA0 * 256;
    const unsigned short* pAH1 = AH + (size_t)rA1 * 256;
    const unsigned short* pAL1 = AL + (size_t)rA1 * 256;

    __syncthreads();

    for (int c = 0; c < 4; ++c) {
        // T14 issue-early: load next chunk into regs (latency hides under MFMA)
        if (c < 3) {
            #pragma unroll
            for (int j = 0; j < 4; ++j) {
                rH[j] = srcH[(c + 1) * 8 + j];
                rL[j] = srcL[(c + 1) * 8 + j];
            }
        }

        #pragma unroll
        for (int ks = 0; ks < 2; ++ks) {
            int krel = c * 64 + ks * 32 + grp * 8;       // 0..248 over [x|agg] row

            bf16x8 ah0 = *(const bf16x8*)(pAH0 + krel);
            bf16x8 al0 = *(const bf16x8*)(pAL0 + krel);
            bf16x8 ah1 = *(const bf16x8*)(pAH1 + krel);
            bf16x8 al1 = *(const bf16x8*)(pAL1 + krel);

            #pragma unroll
            for (int nf = 0; nf < 8; ++nf) {
                int col = nf * 16 + l15;
                bf16x8 bh = *(const bf16x8*)&Bh[col][ks * 32 + grp * 8];
                bf16x8 bl = *(const bf16x8*)&Bl[col][ks * 32 + grp * 8];
                acc[0][nf] = __builtin_amdgcn_mfma_f32_16x16x32_bf16(ah0, bh, acc[0][nf], 0, 0, 0);
                acc[0][nf] = __builtin_amdgcn_mfma_f32_16x16x32_bf16(al0, bh, acc[0][nf], 0, 0, 0);
                acc[0][nf] = __builtin_amdgcn_mfma_f32_16x16x32_bf16(ah0, bl, acc[0][nf], 0, 0, 0);
                acc[1][nf] = __builtin_amdgcn_mfma_f32_16x16x32_bf16(ah1, bh, acc[1][nf], 0, 0, 0);
                acc[1][nf] = __builtin_amdgcn_mfma_f32_16x16x32_bf16(al1, bh, acc[1][nf], 0, 0, 0);
                acc[1][nf] = __builtin_amdgcn_mfma_f32_16x16x32_bf16(ah1, bl, acc[1][nf], 0, 0, 0);
            }
        }

        if (c < 3) {
            __syncthreads();                 // all waves done reading chunk c
            #pragma unroll
            for (int j = 0; j < 4; ++j) { dstH[j] = rH[j]; dstL[j] = rL[j]; }
            __syncthreads();                 // chunk c+1 visible
        }
    }

    // ---- epilogue: +c, ReLU, LayerNorm over 128 cols (wave-local) ----
    float cv[8], gv[8], bv[8];
    #pragma unroll
    for (int nf = 0; nf < 8; ++nf) {
        int col = nf * 16 + l15;
        cv[nf] = cvec[col]; gv[nf] = gamma[col]; bv[nf] = beta[col];
    }

    #pragma unroll
    for (int m = 0; m < 2; ++m) {
        #pragma unroll
        for (int r = 0; r < 4; ++r) {
            float s1 = 0.f, s2 = 0.f;
            #pragma unroll
            for (int nf = 0; nf < 8; ++nf) {
                float v = acc[m][nf][r] + cv[nf];
                v = (v > 0.f) ? v : 0.f;
                acc[m][nf][r] = v;
                s1 += v; s2 += v * v;
            }
            #pragma unroll
            for (int msk = 1; msk < 16; msk <<= 1) {
                s1 += __shfl_xor(s1, msk, 64);
                s2 += __shfl_xor(s2, msk, 64);
            }
            float mu   = s1 * (1.0f / 128.0f);
            float var  = s2 * (1.0f / 128.0f) - mu * mu;
            float rstd = rsqrtf(var + LN_EPS);
            int node = node0 + w * 32 + m * 16 + grp * 4 + r;
            if (node < N_NODES) {
                #pragma unroll
                for (int nf = 0; nf < 8; ++nf)
                    out[(size_t)node * D_FEAT + nf * 16 + l15] =
                        (acc[m][nf][r] - mu) * rstd * gv[nf] + bv[nf];
            }
        }
    }
}

// ---------------------------------------------------------------------------
extern "C" void kernel_launch(void* const* d_in, const int* in_sizes, int n_in,
                              void* d_out, int out_size, void* d_ws, size_t ws_size,
                              hipStream_t stream) {
    const float* x     = (const float*)d_in[0];
    const int*   ei    = (const int*)d_in[1];
    const float* agg_W = (const float*)d_in[2];
    const float* agg_b = (const float*)d_in[3];
    const float* W     = (const float*)d_in[4];
    const float* b     = (const float*)d_in[5];
    const float* gamma = (const float*)d_in[6];
    const float* beta  = (const float*)d_in[7];
    float*       out   = (float*)d_out;

    size_t out_bytes = (size_t)out_size * sizeof(float);

    if (n_in != 8)                       { hipMemsetAsync(d_out, 0x45, out_bytes, stream); return; }
    if (in_sizes[0] != N_NODES * D_FEAT) { hipMemsetAsync(d_out, 0x48, out_bytes, stream); return; }
    if (in_sizes[1] != 2 * N_EDGES)      { hipMemsetAsync(d_out, 0x49, out_bytes, stream); return; }
    if (out_size != N_NODES * D_FEAT)    { hipMemsetAsync(d_out, 0x47, out_bytes, stream); return; }

    // workspace layout (4-byte elements)
    int*   deg_cnt  = (int*)d_ws;                  // 50000
    int*   pos      = deg_cnt + N_NODES;           // 50000
    unsigned short* edge_src = (unsigned short*)(pos + N_NODES);   // NBUCK*BCAP u16
    unsigned short* Wt2h = (unsigned short*)((int*)edge_src + N_EDGES);  // 128*256 bf16
    unsigned short* Wt2l = Wt2h + 128 * 256;                       // 128*256 bf16
    float* cvec     = (float*)(Wt2l + 128 * 256);  // 128
    unsigned short* AH = (unsigned short*)(cvec + 128);            // 50000*256 bf16
    unsigned short* AL = AH + (size_t)N_NODES * 256;               // 50000*256 bf16
    size_t need_ws = ((size_t)N_NODES * 2 + N_EDGES + 256 * 128 + 128) * 4
                     + (size_t)N_NODES * 256 * 2 * 2;
    if (ws_size < need_ws)               { hipMemsetAsync(d_out, 0x46, out_bytes, stream); return; }

    // binned edges + bucket cursors live in d_out (dead until gsage writes out)
    unsigned int* binned = (unsigned int*)d_out;   // NBUCK*BCAP u32 = 4.8 MB
    unsigned int* bcurs  = binned + (size_t)NBUCK * BCAP;     // NBUCK

    hipMemsetAsync(bcurs, 0, NBUCK * sizeof(unsigned int), stream);
    prep_kernel<<<CVT_B + BIN1_B + 128, 256, 0, stream>>>(
        x, ei, agg_W, agg_b, W, b, (uint4*)AH, (uint4*)AL, bcurs, binned,
        Wt2h, Wt2l, cvec);
    binpass2_kernel<<<NBUCK, 512, 0, stream>>>(binned, bcurs, pos, deg_cnt, edge_src);
    gather_kernel<<<(N_NODES + 3) / 4, 256, 0, stream>>>(
        (uint4*)AH, (uint4*)AL, pos, deg_cnt, edge_src);
    gsage_main<<<(N_NODES + TM - 1) / TM, 256, 0, stream>>>(
        AH, AL, Wt2h, Wt2l, cvec, gamma, beta, out);
}

// Round 10
// 172.071 us; speedup vs baseline: 1.1105x; 1.1036x over previous
//
#include <hip/hip_runtime.h>

#define N_NODES 50000
#define N_EDGES 800000
#define D_FEAT 128
#define LN_EPS 1e-5f
#define TM 128         // nodes per block in gsage_main (4 row-slab waves)
#define CVT_B 3125     // blocks for cvt range (800000 threads)
#define NBUCK 391      // ceil(N_NODES/128) dst buckets for binned fill
#define BCAP 3072      // fixed bucket capacity (mean 2048, sigma 45 -> +22s)
#define BIN1_E 4096    // edges per binning block
#define BIN1_B 196     // ceil(N_EDGES/BIN1_E)

typedef __attribute__((ext_vector_type(8))) short bf16x8;
typedef __attribute__((ext_vector_type(4))) float f32x4;

__device__ __forceinline__ unsigned short f2bf(float f) {
    union { float f; unsigned int i; } v; v.f = f;
    unsigned int x = v.i;
    unsigned int lsb = (x >> 16) & 1u;
    x += 0x7fffu + lsb;          // RNE
    return (unsigned short)(x >> 16);
}
__device__ __forceinline__ float bflo(unsigned int u) {
    union { unsigned int i; float f; } v; v.i = u << 16; return v.f;
}
__device__ __forceinline__ float bfhi(unsigned int u) {
    union { unsigned int i; float f; } v; v.i = u & 0xffff0000u; return v.f;
}
__device__ __forceinline__ int clampn(int v) {
    return (v < 0) ? 0 : ((v >= N_NODES) ? (N_NODES - 1) : v);
}
// pack 2 floats -> (hi-bf16 pair, lo-bf16 pair)
__device__ __forceinline__ void split2(float f0, float f1,
                                       unsigned int& hp, unsigned int& lp) {
    unsigned short h0 = f2bf(f0), h1 = f2bf(f1);
    unsigned short l0 = f2bf(f0 - bflo(h0)), l1 = f2bf(f1 - bflo(h1));
    hp = ((unsigned)h1 << 16) | h0;
    lp = ((unsigned)l1 << 16) | l0;
}

// ---------------------------------------------------------------------------
// prep kernel: block-range-split union of
//   [0, CVT_B)            : x fp32 -> AH/AL x-half (bf16 hi/lo planes)
//   [CVT_B, +BIN1_B)      : binpass1 (independent of cvt outputs; overlaps
//                           atomic-bound binning under BW-bound cvt)
//   [CVT_B+BIN1_B, +128)  : wprep row t (fused weight, bf16 hi/lo split,
//                           stored TRANSPOSED [col][k] for MFMA B-frags)
// ---------------------------------------------------------------------------
__global__ __launch_bounds__(256) void prep_kernel(
        const float* __restrict__ x,
        const int* __restrict__ ei,
        const float* __restrict__ agg_W,
        const float* __restrict__ agg_b,
        const float* __restrict__ W,
        const float* __restrict__ b,
        uint4* __restrict__ AH4,
        uint4* __restrict__ AL4,
        unsigned int* __restrict__ bcurs,
        unsigned int* __restrict__ binned,
        unsigned short* __restrict__ Wt2h,
        unsigned short* __restrict__ Wt2l,
        float* __restrict__ cvec)
{
    __shared__ int esrc[BIN1_E];               // 16 KB
    __shared__ unsigned short edst[BIN1_E];    // 8 KB
    __shared__ int hist[NBUCK];
    __shared__ unsigned int cur2[NBUCK];

    int blk = blockIdx.x;
    if (blk < CVT_B) {
        int i = blk * 256 + threadIdx.x;      // 800000 threads, 8 floats each
        const float4 a = *(const float4*)(x + (size_t)i * 8);
        const float4 c = *(const float4*)(x + (size_t)i * 8 + 4);
        uint4 h, l;
        split2(a.x, a.y, h.x, l.x);
        split2(a.z, a.w, h.y, l.y);
        split2(c.x, c.y, h.z, l.z);
        split2(c.z, c.w, h.w, l.w);
        size_t idx = (size_t)(i >> 4) * 32 + (i & 15);   // row*32 + col-chunk
        AH4[idx] = h;
        AL4[idx] = l;
    } else if (blk < CVT_B + BIN1_B) {
        // ---- binpass1 leg: LDS-staged edges, fixed-capacity buckets ----
        int t    = threadIdx.x;
        int base = (blk - CVT_B) * BIN1_E;

        for (int i = t; i < NBUCK; i += 256) hist[i] = 0;
        #pragma unroll
        for (int i = 0; i < BIN1_E / 256; ++i) {
            int idx = i * 256 + t;
            int e = base + idx;
            if (e < N_EDGES) {
                esrc[idx] = clampn(ei[e]);
                edst[idx] = (unsigned short)clampn(ei[N_EDGES + e]);
            } else {
                esrc[idx] = -1;
            }
        }
        __syncthreads();

        #pragma unroll
        for (int i = 0; i < BIN1_E / 256; ++i) {
            int idx = i * 256 + t;
            if (esrc[idx] >= 0) atomicAdd(&hist[(int)edst[idx] >> 7], 1);
        }
        __syncthreads();

        for (int bk = t; bk < NBUCK; bk += 256) {
            int c = hist[bk];
            unsigned int off = c ? atomicAdd(&bcurs[bk], (unsigned int)c) : 0u;
            cur2[bk] = (unsigned int)bk * BCAP + off;
        }
        __syncthreads();

        #pragma unroll
        for (int i = 0; i < BIN1_E / 256; ++i) {
            int idx = i * 256 + t;
            int src = esrc[idx];
            if (src >= 0) {
                int dst = (int)edst[idx];
                int bk  = dst >> 7;
                unsigned int slot = atomicAdd(&cur2[bk], 1u);
                if (slot < (unsigned int)bk * BCAP + BCAP)     // capacity guard
                    binned[slot] = (unsigned int)src | ((unsigned int)dst << 16);
            }
        }
    } else {
        int t = blk - CVT_B - BIN1_B;         // 0..127 (k row)
        int n = threadIdx.x;
        if (n < 128) {
            float w1 = W[t * 128 + n];                      // k=t, col=n
            unsigned short h1 = f2bf(w1);
            Wt2h[n * 256 + t] = h1;
            Wt2l[n * 256 + t] = f2bf(w1 - bflo(h1));
            float m = 0.0f;
            for (int j = 0; j < 128; ++j)
                m += agg_W[t * 128 + j] * W[(128 + j) * 128 + n];
            unsigned short h2 = f2bf(m);                    // k=128+t, col=n
            Wt2h[n * 256 + 128 + t] = h2;
            Wt2l[n * 256 + 128 + t] = f2bf(m - bflo(h2));
            if (t == 0) {
                float s = b[n];
                for (int j = 0; j < 128; ++j)
                    s += agg_b[j] * W[(128 + j) * 128 + n];
                cvec[n] = s;
            }
        }
    }
}

// ---------------------------------------------------------------------------
// binpass2: one block per bucket at fixed base bk*BCAP.  Derives per-node
// degree (LDS count) and bucket-local CSR positions (128-wide LDS scan),
// writes deg_cnt / pos (=end), then scatters src (u16) into the bucket's
// contiguous edge_src region (L2-hot).
// ---------------------------------------------------------------------------
__global__ __launch_bounds__(512) void binpass2_kernel(const unsigned int* __restrict__ binned,
                                                       const unsigned int* __restrict__ bcurs,
                                                       int* __restrict__ pos,
                                                       int* __restrict__ deg_cnt,
                                                       unsigned short* __restrict__ edge_src)
{
    __shared__ int lscan[128];
    __shared__ int lcnt[128];
    __shared__ int lcur[128];
    int bk = blockIdx.x, t = threadIdx.x;

    unsigned int cnt = bcurs[bk]; if (cnt > BCAP) cnt = BCAP;
    unsigned int start = (unsigned int)bk * BCAP;
    unsigned int end   = start + cnt;

    int n0 = bk << 7;
    int nn = N_NODES - n0; if (nn > 128) nn = 128;

    if (t < 128) lcnt[t] = 0;
    __syncthreads();
    for (unsigned int e = start + t; e < end; e += 512)
        atomicAdd(&lcnt[(int)(binned[e] >> 16) & 127], 1);
    __syncthreads();

    // exclusive scan of lcnt[128]
    int lv = (t < 128) ? lcnt[t] : 0;
    if (t < 128) lscan[t] = lv;
    __syncthreads();
    for (int off = 1; off < 128; off <<= 1) {
        int u = (t >= off && t < 128) ? lscan[t - off] : 0;
        __syncthreads();
        if (t < 128) lscan[t] += u;
        __syncthreads();
    }
    if (t < 128) {
        int ls = (int)start + lscan[t] - lv;  // node start (bucket-local CSR)
        lcur[t] = ls;
        if (t < nn) {
            pos[n0 + t]     = ls + lv;        // = end (gather's convention)
            deg_cnt[n0 + t] = lv;
        }
    }
    __syncthreads();

    for (unsigned int e = start + t; e < end; e += 512) {
        unsigned int v = binned[e];
        int slot = atomicAdd(&lcur[(int)(v >> 16) & 127], 1);
        edge_src[slot] = (unsigned short)(v & 0xffffu);
    }
}

// ---------------------------------------------------------------------------
// gather: one wave per node, 4 edges per iteration (quarter-wave per edge,
// uint4 = 8 bf16 hi feats per lane).  Reads AH x-half rows (random, L2/LLC-
// hot); writes the mean into AH/AL agg-half (bf16 hi/lo split -> identical
// numerics to the in-register GEMM split).
// ---------------------------------------------------------------------------
__global__ void gather_kernel(uint4* __restrict__ AH4,
                              uint4* __restrict__ AL4,
                              const int* __restrict__ pos,    // = end
                              const int* __restrict__ deg_cnt,
                              const unsigned short* __restrict__ edge_src)
{
    int tid  = threadIdx.x;
    int node = blockIdx.x * 4 + (tid >> 6);
    int lane = tid & 63;
    int quarter = lane >> 4;
    int sub     = lane & 15;
    if (node >= N_NODES) return;

    int end   = pos[node];
    int dcnt  = deg_cnt[node];
    int start = end - dcnt;

    float a0 = 0.f, a1 = 0.f, a2 = 0.f, a3 = 0.f,
          a4 = 0.f, a5 = 0.f, a6 = 0.f, a7 = 0.f;

    for (int b = start; b < end; b += 64) {
        int nb = end - b; if (nb > 64) nb = 64;
        int sid = (b + lane < end) ? (int)edge_src[b + lane] : 0;
        for (int j = 0; j < nb; j += 4) {
            int eidx = j + quarter;
            int s = __shfl(sid, eidx, 64);
            if (eidx < nb) {
                const uint4 v = AH4[(size_t)s * 32 + sub];   // x-half of row s
                a0 += bflo(v.x); a1 += bfhi(v.x);
                a2 += bflo(v.y); a3 += bfhi(v.y);
                a4 += bflo(v.z); a5 += bfhi(v.z);
                a6 += bflo(v.w); a7 += bfhi(v.w);
            }
        }
    }
    #pragma unroll
    for (int m = 16; m <= 32; m <<= 1) {
        a0 += __shfl_xor(a0, m, 64); a1 += __shfl_xor(a1, m, 64);
        a2 += __shfl_xor(a2, m, 64); a3 += __shfl_xor(a3, m, 64);
        a4 += __shfl_xor(a4, m, 64); a5 += __shfl_xor(a5, m, 64);
        a6 += __shfl_xor(a6, m, 64); a7 += __shfl_xor(a7, m, 64);
    }
    if (quarter == 0) {
        float inv = 1.0f / (float)((dcnt > 1) ? dcnt : 1);
        uint4 h, l;
        split2(a0 * inv, a1 * inv, h.x, l.x);
        split2(a2 * inv, a3 * inv, h.y, l.y);
        split2(a4 * inv, a5 * inv, h.z, l.z);
        split2(a6 * inv, a7 * inv, h.w, l.w);
        size_t idx = (size_t)node * 32 + 16 + sub;           // agg-half
        AH4[idx] = h;
        AL4[idx] = l;
    }
}

// ---------------------------------------------------------------------------
// MFMA GEMM (R7 structure, verified 173.6us — exact revert): A = AH/AL
// planes ([row][256] bf16 hi/lo) x Wt2 (bf16 hi/lo, [col][k]) ->
// Ahi*Whi + Alo*Whi + Ahi*Wlo.  LDS-staged B, in-loop staging, 2 barriers
// per chunk.  R8 (direct-global B) and R9 (T14 reg-prefetch) both regressed
// this by ~16us — gsage is latency/occupancy-bound, NOT stage-latency-bound;
// do not restructure without counter evidence on the critical path.
// Block = 128 nodes, 4 row-slab waves (32 rows x 128 cols, M_rep=2, N_rep=8);
// LayerNorm wave-local.
// ---------------------------------------------------------------------------
__global__ __launch_bounds__(256) void gsage_main(
        const unsigned short* __restrict__ AH,
        const unsigned short* __restrict__ AL,
        const unsigned short* __restrict__ Wt2h,
        const unsigned short* __restrict__ Wt2l,
        const float* __restrict__ cvec,
        const float* __restrict__ gamma,
        const float* __restrict__ beta,
        float* __restrict__ out)
{
    __shared__ unsigned short Bh[128][72];   // 18 KB
    __shared__ unsigned short Bl[128][72];   // 18 KB

    int tid  = threadIdx.x;
    int lane = tid & 63;
    int w    = tid >> 6;                 // row-slab 0..3 (32 rows each)
    int l15  = lane & 15, grp = lane >> 4;
    int node0 = blockIdx.x * TM;

    // staging: thread -> (col, half-row) of the 128x64 bf16 chunk
    int scol  = tid >> 1;
    int spart = tid & 1;
    const uint4* srcH = (const uint4*)Wt2h + scol * 32 + spart * 4;
    const uint4* srcL = (const uint4*)Wt2l + scol * 32 + spart * 4;
    uint4* dstH = (uint4*)&Bh[scol][spart * 32];
    uint4* dstL = (uint4*)&Bl[scol][spart * 32];

    f32x4 acc[2][8];
    #pragma unroll
    for (int m = 0; m < 2; ++m)
        #pragma unroll
        for (int nf = 0; nf < 8; ++nf)
            acc[m][nf] = (f32x4){0.f, 0.f, 0.f, 0.f};

    int row0 = node0 + w * 32 + l15;     // A-frag row for m=0

    for (int c = 0; c < 4; ++c) {
        if (c) __syncthreads();
        #pragma unroll
        for (int j = 0; j < 4; ++j) {
            dstH[j] = srcH[c * 8 + j];
            dstL[j] = srcL[c * 8 + j];
        }
        __syncthreads();

        #pragma unroll
        for (int ks = 0; ks < 2; ++ks) {
            int krel = c * 64 + ks * 32 + grp * 8;       // 0..248 over [x|agg] row

            bf16x8 ah[2], al[2];
            #pragma unroll
            for (int m = 0; m < 2; ++m) {
                int row = row0 + m * 16;
                if (row < N_NODES) {
                    ah[m] = *(const bf16x8*)(AH + (size_t)row * 256 + krel);
                    al[m] = *(const bf16x8*)(AL + (size_t)row * 256 + krel);
                } else {
                    ah[m] = (bf16x8){0,0,0,0,0,0,0,0};
                    al[m] = (bf16x8){0,0,0,0,0,0,0,0};
                }
            }

            #pragma unroll
            for (int nf = 0; nf < 8; ++nf) {
                int col = nf * 16 + l15;
                bf16x8 bh = *(const bf16x8*)&Bh[col][ks * 32 + grp * 8];
                bf16x8 bl = *(const bf16x8*)&Bl[col][ks * 32 + grp * 8];
                #pragma unroll
                for (int m = 0; m < 2; ++m) {
                    acc[m][nf] = __builtin_amdgcn_mfma_f32_16x16x32_bf16(ah[m], bh, acc[m][nf], 0, 0, 0);
                    acc[m][nf] = __builtin_amdgcn_mfma_f32_16x16x32_bf16(al[m], bh, acc[m][nf], 0, 0, 0);
                    acc[m][nf] = __builtin_amdgcn_mfma_f32_16x16x32_bf16(ah[m], bl, acc[m][nf], 0, 0, 0);
                }
            }
        }
    }

    // ---- epilogue: +c, ReLU, LayerNorm over 128 cols (wave-local) ----
    float cv[8], gv[8], bv[8];
    #pragma unroll
    for (int nf = 0; nf < 8; ++nf) {
        int col = nf * 16 + l15;
        cv[nf] = cvec[col]; gv[nf] = gamma[col]; bv[nf] = beta[col];
    }

    #pragma unroll
    for (int m = 0; m < 2; ++m) {
        #pragma unroll
        for (int r = 0; r < 4; ++r) {
            float s1 = 0.f, s2 = 0.f;
            #pragma unroll
            for (int nf = 0; nf < 8; ++nf) {
                float v = acc[m][nf][r] + cv[nf];
                v = (v > 0.f) ? v : 0.f;
                acc[m][nf][r] = v;
                s1 += v; s2 += v * v;
            }
            #pragma unroll
            for (int msk = 1; msk < 16; msk <<= 1) {
                s1 += __shfl_xor(s1, msk, 64);
                s2 += __shfl_xor(s2, msk, 64);
            }
            float mu   = s1 * (1.0f / 128.0f);
            float var  = s2 * (1.0f / 128.0f) - mu * mu;
            float rstd = rsqrtf(var + LN_EPS);
            int node = node0 + w * 32 + m * 16 + grp * 4 + r;
            if (node < N_NODES) {
                #pragma unroll
                for (int nf = 0; nf < 8; ++nf)
                    out[(size_t)node * D_FEAT + nf * 16 + l15] =
                        (acc[m][nf][r] - mu) * rstd * gv[nf] + bv[nf];
            }
        }
    }
}

// ---------------------------------------------------------------------------
extern "C" void kernel_launch(void* const* d_in, const int* in_sizes, int n_in,
                              void* d_out, int out_size, void* d_ws, size_t ws_size,
                              hipStream_t stream) {
    const float* x     = (const float*)d_in[0];
    const int*   ei    = (const int*)d_in[1];
    const float* agg_W = (const float*)d_in[2];
    const float* agg_b = (const float*)d_in[3];
    const float* W     = (const float*)d_in[4];
    const float* b     = (const float*)d_in[5];
    const float* gamma = (const float*)d_in[6];
    const float* beta  = (const float*)d_in[7];
    float*       out   = (float*)d_out;

    size_t out_bytes = (size_t)out_size * sizeof(float);

    if (n_in != 8)                       { hipMemsetAsync(d_out, 0x45, out_bytes, stream); return; }
    if (in_sizes[0] != N_NODES * D_FEAT) { hipMemsetAsync(d_out, 0x48, out_bytes, stream); return; }
    if (in_sizes[1] != 2 * N_EDGES)      { hipMemsetAsync(d_out, 0x49, out_bytes, stream); return; }
    if (out_size != N_NODES * D_FEAT)    { hipMemsetAsync(d_out, 0x47, out_bytes, stream); return; }

    // workspace layout (4-byte elements)
    int*   deg_cnt  = (int*)d_ws;                  // 50000
    int*   pos      = deg_cnt + N_NODES;           // 50000
    unsigned short* edge_src = (unsigned short*)(pos + N_NODES);   // NBUCK*BCAP u16
    unsigned short* Wt2h = (unsigned short*)((int*)edge_src + N_EDGES);  // 128*256 bf16
    unsigned short* Wt2l = Wt2h + 128 * 256;                       // 128*256 bf16
    float* cvec     = (float*)(Wt2l + 128 * 256);  // 128
    unsigned short* AH = (unsigned short*)(cvec + 128);            // 50000*256 bf16
    unsigned short* AL = AH + (size_t)N_NODES * 256;               // 50000*256 bf16
    size_t need_ws = ((size_t)N_NODES * 2 + N_EDGES + 256 * 128 + 128) * 4
                     + (size_t)N_NODES * 256 * 2 * 2;
    if (ws_size < need_ws)               { hipMemsetAsync(d_out, 0x46, out_bytes, stream); return; }

    // binned edges + bucket cursors live in d_out (dead until gsage writes out)
    unsigned int* binned = (unsigned int*)d_out;   // NBUCK*BCAP u32 = 4.8 MB
    unsigned int* bcurs  = binned + (size_t)NBUCK * BCAP;     // NBUCK

    hipMemsetAsync(bcurs, 0, NBUCK * sizeof(unsigned int), stream);
    prep_kernel<<<CVT_B + BIN1_B + 128, 256, 0, stream>>>(
        x, ei, agg_W, agg_b, W, b, (uint4*)AH, (uint4*)AL, bcurs, binned,
        Wt2h, Wt2l, cvec);
    binpass2_kernel<<<NBUCK, 512, 0, stream>>>(binned, bcurs, pos, deg_cnt, edge_src);
    gather_kernel<<<(N_NODES + 3) / 4, 256, 0, stream>>>(
        (uint4*)AH, (uint4*)AL, pos, deg_cnt, edge_src);
    gsage_main<<<(N_NODES + TM - 1) / TM, 256, 0, stream>>>(
        AH, AL, Wt2h, Wt2l, cvec, gamma, beta, out);
}